// Round 10
// baseline (1458.768 us; speedup 1.0000x reference)
//
#include <hip/hip_runtime.h>
#include <stdint.h>

typedef __attribute__((ext_vector_type(8))) short bf16x8;
typedef __attribute__((ext_vector_type(4))) short bf16x4;
typedef __attribute__((ext_vector_type(4))) float f32x4;

#define DEV static __device__ __forceinline__
#define SB() __builtin_amdgcn_sched_barrier(0)

DEV float bf2f(short u) {
    union { float f; uint32_t i; } v;
    v.i = ((uint32_t)(uint16_t)u) << 16;
    return v.f;
}
DEV short f2bf(float f) {
    union { float f; uint32_t i; } v; v.f = f;
    uint32_t r = v.i + 0x7fff + ((v.i >> 16) & 1);
    return (short)(r >> 16);
}

DEV void gload_lds16(const void* g, void* l) {
    __builtin_amdgcn_global_load_lds(
        (__attribute__((address_space(1))) void*)(void*)g,
        (__attribute__((address_space(3))) void*)l,
        16, 0, 0);
}

// ---------------- f32 -> bf16 conversion ----------------
__global__ __launch_bounds__(256) void cvt_kernel(const float* __restrict__ in,
                                                  ushort* __restrict__ out, int n4) {
    int idx = blockIdx.x * 256 + threadIdx.x;
    int stride = gridDim.x * 256;
    for (int i = idx; i < n4; i += stride) {
        float4 v = ((const float4*)in)[i];
        bf16x4 o;
        o.x = f2bf(v.x); o.y = f2bf(v.y); o.z = f2bf(v.z); o.w = f2bf(v.w);
        ((bf16x4*)out)[i] = o;
    }
}

// ==== 256x256 GEMM: A via LDS dbuf (64 KB), B via register streaming ====
// flatmm-style: B weight panel (L2-hot) loads straight to VGPRs one tile
// ahead (8 x dwordx4/wave, dbuf'd reg sets); A staged via global_load_lds
// into [256][64] XOR-swizzled LDS (R7-verified conflict-free).
// Per tile t: {R0,R1: 8 A-reads ; stageA(t+1) ; vmcnt(4)->B(t) certified ;
// loadB(t+1)->bN ; lgkm(4) c0 ; R2 ; lgkm(4) c1 ; R3 ; lgkm(4) c2 ;
// lgkm(0) c3 ; vmcnt(8)->A(t+1) certified ; barrier}.  All gates counted;
// gate-then-barrier for DMA visibility; vmcnt(0) only in the last tile.
// MODE 0: relu(acc+bias) -> bf16 ;  MODE 1: acc+bias -> bf16
template<int MODE>
__global__ __launch_bounds__(512, 2) void gemm256(
    const ushort* __restrict__ A,
    const ushort* __restrict__ Bw,
    const float* __restrict__ bias,
    ushort* __restrict__ Cb,
    int M, int N, int K,
    long sA, long sB, long sBias, long sC)
{
    __shared__ ushort lA[2][16384];   // 2 x 32 KB (A only)

    const int z = blockIdx.z;
    const ushort* Az = A + (size_t)z * sA;
    const ushort* Bz = Bw + (size_t)z * sB;
    const float*  bz = bias + (size_t)z * sBias;
    ushort*       Cz = Cb + (size_t)z * sC;

    const int tid  = threadIdx.x;
    const int lane = tid & 63;
    const int wid  = tid >> 6;        // 0..7
    const int wr   = wid >> 2;        // 0..1  (128 rows)
    const int wc   = wid & 3;         // 0..3  (64 cols)
    const int fr   = lane & 15;
    const int hi   = lane >> 4;       // 0..3
    const int m0   = blockIdx.x * 256;
    const int n0   = blockIdx.y * 256;

    // A frag-read swizzled k-offsets (lane-constant)
    const int fr8 = fr & 7;
    const int sw0 = ((0 + hi) ^ fr8) * 8;   // kf=0
    const int sw1 = ((4 + hi) ^ fr8) * 8;   // kf=1
    const int ar0 = wr * 128 + fr;

    // A staging: pass p, unit g = p*512 + tid; row = g>>3; ku = (g&7)^(row&7)
    long offA[4];
    int  dstU[4];
#pragma unroll
    for (int p = 0; p < 4; p++) {
        const int g   = p * 512 + tid;
        const int row = g >> 3;
        const int ku  = (g & 7) ^ (row & 7);
        offA[p] = (long)(m0 + row) * K + ku * 8;
        dstU[p] = (p * 512 + wid * 64) * 8;
    }
    auto stA = [&](int bi, long kt) {
#pragma unroll
        for (int p = 0; p < 4; p++)
            gload_lds16(Az + offA[p] + kt, &lA[bi][dstU[p]]);
    };

    // B per-lane row pointers (global, L2-hot weight panel)
    const ushort* Brow[4];
#pragma unroll
    for (int j = 0; j < 4; j++)
        Brow[j] = Bz + (size_t)(n0 + wc * 64 + j * 16 + fr) * K + hi * 8;
    auto loadB = [&](long kt, bf16x8 (&b)[8]) {
#pragma unroll
        for (int kf = 0; kf < 2; kf++)
#pragma unroll
            for (int j = 0; j < 4; j++)
                b[kf * 4 + j] = *(const bf16x8*)(Brow[j] + kt + kf * 32);
    };

    f32x4 acc[8][4];
#pragma unroll
    for (int i = 0; i < 8; i++)
#pragma unroll
        for (int j = 0; j < 4; j++) acc[i][j] = (f32x4){0.f, 0.f, 0.f, 0.f};

    bf16x8 bEv[8], bOd[8];
    const int NT = K >> 6;   // BK=64

    // prologue: A(0) staged+certified; B(0) -> bEv (in flight, per-wave regs)
    stA(0, 0);
    loadB(0, bEv);
    asm volatile("s_waitcnt vmcnt(8)" ::: "memory");   // A(0) landed
    __builtin_amdgcn_s_barrier();
    SB();

    auto tile = [&](int t, bf16x8 (&bC)[8], bf16x8 (&bN)[8]) {
        const int bi = t & 1, nb = bi ^ 1;
        const long ktn = (long)(t + 1) << 6;
        const ushort* la = lA[bi];
        bf16x8 aE[4], aEm[4], aO[4], aOm[4];

        // R0 + R1: A kf0 frags (8 reads)
#pragma unroll
        for (int i = 0; i < 4; i++)
            aE[i] = *(const bf16x8*)&la[(ar0 + i * 16) * 64 + sw0];
#pragma unroll
        for (int i = 0; i < 4; i++)
            aEm[i] = *(const bf16x8*)&la[(ar0 + 64 + i * 16) * 64 + sw0];
        SB();
        if (t + 1 < NT) stA(nb, ktn);
        // B(t) certification: only A(t+1)'s 4 gloads may remain in flight
        if (t + 1 < NT) asm volatile("s_waitcnt vmcnt(4)" ::: "memory");
        else            asm volatile("s_waitcnt vmcnt(0)" ::: "memory");
        SB();
        if (t + 1 < NT) loadB(ktn, bN);
        SB();

        asm volatile("s_waitcnt lgkmcnt(4)" ::: "memory");   // R0 ready
        SB();
        __builtin_amdgcn_s_setprio(1);
#pragma unroll
        for (int i = 0; i < 4; i++)
#pragma unroll
            for (int j = 0; j < 4; j++)
                acc[i][j] = __builtin_amdgcn_mfma_f32_16x16x32_bf16(
                    aE[i], bC[j], acc[i][j], 0, 0, 0);
        __builtin_amdgcn_s_setprio(0);
        SB();

        // R2: A kf1 mh0 (4 reads)
#pragma unroll
        for (int i = 0; i < 4; i++)
            aO[i] = *(const bf16x8*)&la[(ar0 + i * 16) * 64 + sw1];
        SB();
        asm volatile("s_waitcnt lgkmcnt(4)" ::: "memory");   // R1 ready
        SB();
        __builtin_amdgcn_s_setprio(1);
#pragma unroll
        for (int i = 0; i < 4; i++)
#pragma unroll
            for (int j = 0; j < 4; j++)
                acc[4 + i][j] = __builtin_amdgcn_mfma_f32_16x16x32_bf16(
                    aEm[i], bC[j], acc[4 + i][j], 0, 0, 0);
        __builtin_amdgcn_s_setprio(0);
        SB();

        // R3: A kf1 mh1 (4 reads)
#pragma unroll
        for (int i = 0; i < 4; i++)
            aOm[i] = *(const bf16x8*)&la[(ar0 + 64 + i * 16) * 64 + sw1];
        SB();
        asm volatile("s_waitcnt lgkmcnt(4)" ::: "memory");   // R2 ready
        SB();
        __builtin_amdgcn_s_setprio(1);
#pragma unroll
        for (int i = 0; i < 4; i++)
#pragma unroll
            for (int j = 0; j < 4; j++)
                acc[i][j] = __builtin_amdgcn_mfma_f32_16x16x32_bf16(
                    aO[i], bC[4 + j], acc[i][j], 0, 0, 0);
        __builtin_amdgcn_s_setprio(0);
        SB();

        asm volatile("s_waitcnt lgkmcnt(0)" ::: "memory");   // R3 ready
        SB();
        __builtin_amdgcn_s_setprio(1);
#pragma unroll
        for (int i = 0; i < 4; i++)
#pragma unroll
            for (int j = 0; j < 4; j++)
                acc[4 + i][j] = __builtin_amdgcn_mfma_f32_16x16x32_bf16(
                    aOm[i], bC[4 + j], acc[4 + i][j], 0, 0, 0);
        __builtin_amdgcn_s_setprio(0);

        // A(t+1) certification BEFORE barrier (B(t+1)'s 8 reg-loads may fly)
        if (t + 1 < NT) {
            asm volatile("s_waitcnt vmcnt(8)" ::: "memory");
            __builtin_amdgcn_s_barrier();
        }
        SB();
    };

    for (int t = 0; t < NT; t += 2) {
        tile(t,     bEv, bOd);
        tile(t + 1, bOd, bEv);
    }

    // Epilogue. C/D layout (m89-verified): col = lane&15, row = (lane>>4)*4 + q
    const int cr = hi * 4;
    const int cc = fr;
#pragma unroll
    for (int m = 0; m < 8; m++) {
        const int row = m0 + wr * 128 + m * 16 + cr;
#pragma unroll
        for (int n = 0; n < 4; n++) {
            const int col = n0 + wc * 64 + n * 16 + cc;
            const float bv = bz[col];
#pragma unroll
            for (int q = 0; q < 4; q++) {
                float v = acc[m][n][q] + bv;
                if (MODE == 0) v = v > 0.f ? v : 0.f;
                Cz[(size_t)(row + q) * N + col] = (ushort)f2bf(v);
            }
        }
    }
}

// ---------------- small 128x128 GEMM (gate layer) ----------------
template<int MODE>
__global__ __launch_bounds__(256) void gemm_bt(
    const ushort* __restrict__ A,
    const ushort* __restrict__ Bw,
    const float* __restrict__ bias,
    ushort* __restrict__ Cb,
    int M, int N, int K)
{
    __shared__ ushort lA[128 * 64];
    __shared__ ushort lB[128 * 64];

    const int tid  = threadIdx.x;
    const int lane = tid & 63;
    const int wv   = tid >> 6;
    const int wr   = wv >> 1;
    const int wc   = wv & 1;
    const int m0   = blockIdx.x * 128;
    const int n0   = blockIdx.y * 128;

    const int srow = lane >> 3;
    const int scol = (lane & 7) * 8;
    const int fr   = lane & 15;
    const int fk   = (lane >> 4) * 8;

    f32x4 zero4 = {0.f, 0.f, 0.f, 0.f};
    f32x4 acc[4][4];
#pragma unroll
    for (int i = 0; i < 4; i++)
#pragma unroll
        for (int j = 0; j < 4; j++) acc[i][j] = zero4;

    for (int kt = 0; kt < K; kt += 64) {
        __syncthreads();
#pragma unroll
        for (int i = 0; i < 4; i++) {
            const int chunk = wv * 4 + i;
            const int row   = chunk * 8 + srow;
            gload_lds16(A  + (size_t)(m0 + row) * K + kt + scol, &lA[chunk * 512]);
            gload_lds16(Bw + (size_t)(n0 + row) * K + kt + scol, &lB[chunk * 512]);
        }
        __syncthreads();

#pragma unroll
        for (int ks = 0; ks < 2; ks++) {
            bf16x8 aF[4], bF[4];
#pragma unroll
            for (int i = 0; i < 4; i++)
                aF[i] = *(const bf16x8*)&lA[(wr * 64 + i * 16 + fr) * 64 + ks * 32 + fk];
#pragma unroll
            for (int j = 0; j < 4; j++)
                bF[j] = *(const bf16x8*)&lB[(wc * 64 + j * 16 + fr) * 64 + ks * 32 + fk];
#pragma unroll
            for (int i = 0; i < 4; i++)
#pragma unroll
                for (int j = 0; j < 4; j++)
                    acc[i][j] = __builtin_amdgcn_mfma_f32_16x16x32_bf16(
                        aF[i], bF[j], acc[i][j], 0, 0, 0);
        }
    }

    const int cr = (lane >> 4) * 4;
    const int cc = lane & 15;
#pragma unroll
    for (int i = 0; i < 4; i++) {
#pragma unroll
        for (int j = 0; j < 4; j++) {
            const int col = n0 + wc * 64 + j * 16 + cc;
            const float bv = bias[col];
#pragma unroll
            for (int q = 0; q < 4; q++) {
                const int row = m0 + wr * 64 + i * 16 + cr + q;
                float v = acc[i][j][q] + bv;
                if (MODE == 0) v = v > 0.f ? v : 0.f;
                Cb[(size_t)row * N + col] = (ushort)f2bf(v);
            }
        }
    }
}

// ---------------- LayerNorm + relu + residual (in place on z) ----------------
__global__ __launch_bounds__(256) void ln_kernel(
    ushort* __restrict__ z, const ushort* __restrict__ h,
    const float* __restrict__ g, const float* __restrict__ b, int B, int H)
{
    const int r = blockIdx.x;
    const int e = blockIdx.y;
    const int t = threadIdx.x;
    const size_t base = ((size_t)e * B + r) * H + t * 4;
    const float* ge = g + (size_t)e * H;
    const float* be = b + (size_t)e * H;

    bf16x4 zv = *(const bf16x4*)&z[base];
    float zf[4];
#pragma unroll
    for (int j = 0; j < 4; j++) zf[j] = bf2f(zv[j]);

    float s  = zf[0] + zf[1] + zf[2] + zf[3];
    float s2 = zf[0]*zf[0] + zf[1]*zf[1] + zf[2]*zf[2] + zf[3]*zf[3];
#pragma unroll
    for (int off = 32; off; off >>= 1) {
        s  += __shfl_xor(s, off);
        s2 += __shfl_xor(s2, off);
    }
    __shared__ float red[8];
    const int wv = t >> 6, lane = t & 63;
    if (lane == 0) { red[wv] = s; red[4 + wv] = s2; }
    __syncthreads();
    s  = red[0] + red[1] + red[2] + red[3];
    s2 = red[4] + red[5] + red[6] + red[7];

    const float mu  = s / (float)H;
    const float var = s2 / (float)H - mu * mu;
    const float rs  = rsqrtf(var + 1e-5f);

    bf16x4 hv = *(const bf16x4*)&h[base];
    bf16x4 o;
#pragma unroll
    for (int j = 0; j < 4; j++) {
        float gn = (zf[j] - mu) * rs * ge[t * 4 + j] + be[t * 4 + j];
        gn = gn > 0.f ? gn : 0.f;
        o[j] = f2bf(gn + bf2f(hv[j]));
    }
    *(bf16x4*)&z[base] = o;
}

// ---------------- gate: logits = gh @ Wg2^T + bg2 ; softmax over 8 ----------
__global__ __launch_bounds__(256) void gate2_kernel(
    const ushort* __restrict__ gh,   // [B,256] bf16
    const float* __restrict__ Wg2,   // [8,256]
    const float* __restrict__ bg2,   // [8]
    float* __restrict__ gate)        // [B,8]
{
    const int wv = threadIdx.x >> 6, lane = threadIdx.x & 63;
    const int r = blockIdx.x * 4 + wv;

    bf16x4 v = *(const bf16x4*)&gh[(size_t)r * 256 + lane * 4];
    float gf[4];
#pragma unroll
    for (int j = 0; j < 4; j++) gf[j] = bf2f(v[j]);

    float lg[8];
#pragma unroll
    for (int e = 0; e < 8; e++) {
        const float* w = Wg2 + e * 256 + lane * 4;
        float p = gf[0]*w[0] + gf[1]*w[1] + gf[2]*w[2] + gf[3]*w[3];
#pragma unroll
        for (int off = 32; off; off >>= 1) p += __shfl_xor(p, off);
        lg[e] = p + bg2[e];
    }
    float mx = lg[0];
#pragma unroll
    for (int e = 1; e < 8; e++) mx = fmaxf(mx, lg[e]);
    float ex[8], ssum = 0.f;
#pragma unroll
    for (int e = 0; e < 8; e++) { ex[e] = expf(lg[e] - mx); ssum += ex[e]; }
    const float inv = 1.f / ssum;
    float myex = 0.f;
#pragma unroll
    for (int e = 0; e < 8; e++) myex = (lane == e) ? ex[e] : myex;
    if (lane < 8) gate[(size_t)r * 8 + lane] = myex * inv;
}

// ---------------- gated combine: out (+)= sum_el gate[b,e0+el] * eo[el,b,:] --
__global__ __launch_bounds__(256) void combine_kernel(
    const ushort* __restrict__ eo,   // [eg, B, D] bf16
    const float* __restrict__ gate,  // [B, 8]
    float* __restrict__ out,         // [B, D]
    int total4, int e0, int eg, int init)
{
    const size_t BD = (size_t)8192 * 1024;
    int idx = blockIdx.x * 256 + threadIdx.x;
    int stride = gridDim.x * 256;
    for (int t = idx; t < total4; t += stride) {
        int b = t >> 8;                 // D/4 = 256
        int d = (t & 255) << 2;
        float4 s = {0.f, 0.f, 0.f, 0.f};
        for (int el = 0; el < eg; el++) {
            const float g = gate[(size_t)b * 8 + e0 + el];
            bf16x4 v = *(const bf16x4*)&eo[(size_t)el * BD + (size_t)b * 1024 + d];
            s.x += g * bf2f(v.x);
            s.y += g * bf2f(v.y);
            s.z += g * bf2f(v.z);
            s.w += g * bf2f(v.w);
        }
        float4* o = (float4*)&out[(size_t)b * 1024 + d];
        if (init) *o = s;
        else {
            float4 p = *o;
            p.x += s.x; p.y += s.y; p.z += s.z; p.w += s.w;
            *o = p;
        }
    }
}

// ---------------- host ----------------
extern "C" void kernel_launch(void* const* d_in, const int* in_sizes, int n_in,
                              void* d_out, int out_size, void* d_ws, size_t ws_size,
                              hipStream_t stream)
{
    const float* x   = (const float*)d_in[0];
    const float* W0  = (const float*)d_in[1];
    const float* b0  = (const float*)d_in[2];
    const float* W1  = (const float*)d_in[3];
    const float* b1  = (const float*)d_in[4];
    const float* lng = (const float*)d_in[5];
    const float* lnb = (const float*)d_in[6];
    const float* W2  = (const float*)d_in[7];
    const float* b2  = (const float*)d_in[8];
    const float* Wg1 = (const float*)d_in[9];
    const float* bg1 = (const float*)d_in[10];
    const float* Wg2 = (const float*)d_in[11];
    const float* bg2 = (const float*)d_in[12];
    float* out = (float*)d_out;

    const int B = 8192, D = 1024, H = 1024, E = 8, G = 256;

    char* ws = (char*)d_ws;
    ushort* x_bf  = (ushort*)ws;  ws += (size_t)B * D * 2;
    ushort* w0_bf = (ushort*)ws;  ws += (size_t)E * H * D * 2;
    ushort* w1_bf = (ushort*)ws;  ws += (size_t)E * H * H * 2;
    ushort* w2_bf = (ushort*)ws;  ws += (size_t)E * D * H * 2;
    ushort* wg1bf = (ushort*)ws;  ws += (size_t)G * D * 2;
    ushort* gh_bf = (ushort*)ws;  ws += (size_t)B * G * 2;
    float*  gatep = (float*)ws;   ws += (size_t)B * E * 4;

    size_t used  = (size_t)(ws - (char*)d_ws);
    size_t avail = (ws_size > used) ? ws_size - used : 0;
    size_t per_eg = (size_t)B * H * 2 * 2;   // h-buf + z-buf per expert
    int EG = 1;
    for (int cand = 8; cand >= 1; cand >>= 1)
        if ((size_t)cand * per_eg <= avail) { EG = cand; break; }

    ushort* hbuf = (ushort*)ws;
    ushort* zbuf = (ushort*)(ws + (size_t)EG * B * H * 2);

    auto cvt = [&](const float* src, ushort* dst, size_t n) {
        int n4 = (int)(n / 4);
        int blocks = (n4 + 255) / 256;
        if (blocks > 2048) blocks = 2048;
        cvt_kernel<<<dim3(blocks), dim3(256), 0, stream>>>(src, dst, n4);
    };
    cvt(x,   x_bf,  (size_t)B * D);
    cvt(W0,  w0_bf, (size_t)E * H * D);
    cvt(W1,  w1_bf, (size_t)E * H * H);
    cvt(W2,  w2_bf, (size_t)E * D * H);
    cvt(Wg1, wg1bf, (size_t)G * D);

    // gate
    gemm_bt<0><<<dim3(B / 128, G / 128), dim3(256), 0, stream>>>(
        x_bf, wg1bf, bg1, gh_bf, B, G, D);
    gate2_kernel<<<dim3(B / 4), dim3(256), 0, stream>>>(gh_bf, Wg2, bg2, gatep);

    const int cb4 = 2048;
    for (int e0 = 0; e0 < E; e0 += EG) {
        const int eg = (E - e0 < EG) ? (E - e0) : EG;
        // layer0: h = relu(x @ W0[e]^T + b0[e])
        gemm256<0><<<dim3(B / 256, H / 256, eg), dim3(512), 0, stream>>>(
            x_bf, w0_bf + (size_t)e0 * H * D, b0 + (size_t)e0 * H, hbuf,
            B, H, D, 0, (long)H * D, H, (long)B * H);
        // layer1: z = h @ W1[e]^T + b1[e]
        gemm256<1><<<dim3(B / 256, H / 256, eg), dim3(512), 0, stream>>>(
            hbuf, w1_bf + (size_t)e0 * H * H, b1 + (size_t)e0 * H, zbuf,
            B, H, H, (long)B * H, (long)H * H, H, (long)B * H);
        // LN -> relu -> +h
        ln_kernel<<<dim3(B, eg), dim3(256), 0, stream>>>(
            zbuf, hbuf, lng + (size_t)e0 * H, lnb + (size_t)e0 * H, B, H);
        // layer2: eo = hp @ W2[e]^T + b2[e]  (into hbuf)
        gemm256<1><<<dim3(B / 256, D / 256, eg), dim3(512), 0, stream>>>(
            zbuf, w2_bf + (size_t)e0 * D * H, b2 + (size_t)e0 * D, hbuf,
            B, D, H, (long)B * H, (long)D * H, D, (long)B * D);
        // gated combine
        combine_kernel<<<dim3(cb4), dim3(256), 0, stream>>>(
            hbuf, gatep, out, B * (D / 4), e0, eg, (e0 == 0) ? 1 : 0);
    }
}

// Round 12
// 581.429 us; speedup vs baseline: 2.5089x; 2.5089x over previous
//
#include <hip/hip_runtime.h>
#include <stdint.h>

typedef __attribute__((ext_vector_type(8))) short bf16x8;
typedef __attribute__((ext_vector_type(4))) short bf16x4;
typedef __attribute__((ext_vector_type(4))) float f32x4;

#define DEV static __device__ __forceinline__
#define SB() __builtin_amdgcn_sched_barrier(0)

DEV float bf2f(short u) {
    union { float f; uint32_t i; } v;
    v.i = ((uint32_t)(uint16_t)u) << 16;
    return v.f;
}
DEV short f2bf(float f) {
    union { float f; uint32_t i; } v; v.f = f;
    uint32_t r = v.i + 0x7fff + ((v.i >> 16) & 1);
    return (short)(r >> 16);
}

DEV void gload_lds16(const void* g, void* l) {
    __builtin_amdgcn_global_load_lds(
        (__attribute__((address_space(1))) void*)(void*)g,
        (__attribute__((address_space(3))) void*)l,
        16, 0, 0);
}

// ---------------- f32 -> bf16 conversion ----------------
__global__ __launch_bounds__(256) void cvt_kernel(const float* __restrict__ in,
                                                  ushort* __restrict__ out, int n4) {
    int idx = blockIdx.x * 256 + threadIdx.x;
    int stride = gridDim.x * 256;
    for (int i = idx; i < n4; i += stride) {
        float4 v = ((const float4*)in)[i];
        bf16x4 o;
        o.x = f2bf(v.x); o.y = f2bf(v.y); o.z = f2bf(v.z); o.w = f2bf(v.w);
        ((bf16x4*)out)[i] = o;
    }
}

// ==== 256x256 GEMM, BK=64, dbuf, reads-ahead + descending counted lgkm ====
// LDS per buf: row-major [256 rows][64 k] bf16 (32 KB), 16B-unit XOR swizzle
// ku ^= (row&7)  (R7/R9-verified: 0 bank conflicts, coalesced 128B staging).
// Per tile t (read buf bi=t&1, stage buf nb); lgkmcnt is 4-bit (max 15):
//   issue R0(8: aE+bE) R1(4: aEm) R2(8: aO+bO);  stageA+stageB(t+1) [8 DMA];
//   lgkm(12)->c0 [R1+R2 fly] ; issue R3(4: aOm) ;
//   lgkm(12)->c1 [R2+R3 fly] ; lgkm(4)->c2 ; lgkm(0)->c3 ;
//   vmcnt(0) [DMA issued a full tile ago -> near-free] ; BARRIER.
// R2 services under c0/c1, R3 under c1/c2; one barrier/tile.
// MODE 0: relu(acc+bias) -> bf16 ;  MODE 1: acc+bias -> bf16
template<int MODE>
__global__ __launch_bounds__(512, 2) void gemm256(
    const ushort* __restrict__ A,
    const ushort* __restrict__ Bw,
    const float* __restrict__ bias,
    ushort* __restrict__ Cb,
    int M, int N, int K,
    long sA, long sB, long sBias, long sC)
{
    __shared__ ushort lA[2][16384];   // 2 x 32 KB
    __shared__ ushort lB[2][16384];

    const int z = blockIdx.z;
    const ushort* Az = A + (size_t)z * sA;
    const ushort* Bz = Bw + (size_t)z * sB;
    const float*  bz = bias + (size_t)z * sBias;
    ushort*       Cz = Cb + (size_t)z * sC;

    const int tid  = threadIdx.x;
    const int lane = tid & 63;
    const int wid  = tid >> 6;        // 0..7
    const int wr   = wid >> 2;        // 0..1  (128 rows)
    const int wc   = wid & 3;         // 0..3  (64 cols)
    const int fr   = lane & 15;
    const int hi   = lane >> 4;       // 0..3
    const int m0   = blockIdx.x * 256;
    const int n0   = blockIdx.y * 256;

    // lane-constant swizzled k-offsets (ushorts) for frag reads
    const int fr8 = fr & 7;
    const int sw0 = ((0 + hi) ^ fr8) * 8;   // kf=0
    const int sw1 = ((4 + hi) ^ fr8) * 8;   // kf=1
    const int ar0 = wr * 128 + fr;
    const int br0 = wc * 64 + fr;

    // staging: pass p, unit g = p*512 + tid; row = g>>3; ku = (g&7)^(row&7)
    long offA[4], offB[4];
    int  dstU[4];
#pragma unroll
    for (int p = 0; p < 4; p++) {
        const int g   = p * 512 + tid;
        const int row = g >> 3;
        const int ku  = (g & 7) ^ (row & 7);
        offA[p] = (long)(m0 + row) * K + ku * 8;
        offB[p] = (long)(n0 + row) * K + ku * 8;
        dstU[p] = (p * 512 + wid * 64) * 8;   // wave-uniform ushort index
    }

    auto stA = [&](int bi, long kt) {
#pragma unroll
        for (int p = 0; p < 4; p++)
            gload_lds16(Az + offA[p] + kt, &lA[bi][dstU[p]]);
    };
    auto stB = [&](int bi, long kt) {
#pragma unroll
        for (int p = 0; p < 4; p++)
            gload_lds16(Bz + offB[p] + kt, &lB[bi][dstU[p]]);
    };

    f32x4 acc[8][4];
#pragma unroll
    for (int i = 0; i < 8; i++)
#pragma unroll
        for (int j = 0; j < 4; j++) acc[i][j] = (f32x4){0.f, 0.f, 0.f, 0.f};

    const int NT = K >> 6;   // BK=64

    // prologue: tile 0 fully staged and drained
    stA(0, 0); stB(0, 0);
    asm volatile("s_waitcnt vmcnt(0)" ::: "memory");
    __builtin_amdgcn_s_barrier();
    SB();

    for (int t = 0; t < NT; t++) {
        const int bi = t & 1, nb = bi ^ 1;
        const long ktn = (long)(t + 1) << 6;
        const ushort* la = lA[bi];
        const ushort* lb = lB[bi];
        bf16x8 aE[4], bE[4], aEm[4], aO[4], bO[4], aOm[4];

        // ---- R0: kf0 mh0 (8 reads) ----
#pragma unroll
        for (int i = 0; i < 4; i++)
            aE[i] = *(const bf16x8*)&la[(ar0 + i * 16) * 64 + sw0];
#pragma unroll
        for (int j = 0; j < 4; j++)
            bE[j] = *(const bf16x8*)&lb[(br0 + j * 16) * 64 + sw0];
        SB();
        // ---- R1: kf0 mh1 (4 reads) ----
#pragma unroll
        for (int i = 0; i < 4; i++)
            aEm[i] = *(const bf16x8*)&la[(ar0 + 64 + i * 16) * 64 + sw0];
        SB();
        // ---- R2: kf1 mh0 (8 reads) ----
#pragma unroll
        for (int i = 0; i < 4; i++)
            aO[i] = *(const bf16x8*)&la[(ar0 + i * 16) * 64 + sw1];
#pragma unroll
        for (int j = 0; j < 4; j++)
            bO[j] = *(const bf16x8*)&lb[(br0 + j * 16) * 64 + sw1];
        SB();

        // ---- stage next tile (8 DMA, full-tile window to land) ----
        if (t + 1 < NT) { stA(nb, ktn); stB(nb, ktn); }
        SB();

        // ---- c0: aE x bE  (R1+R2 = 12 outstanding) ----
        asm volatile("s_waitcnt lgkmcnt(12)" ::: "memory");   // R0 ready
        SB();
        __builtin_amdgcn_s_setprio(1);
#pragma unroll
        for (int i = 0; i < 4; i++)
#pragma unroll
            for (int j = 0; j < 4; j++)
                acc[i][j] = __builtin_amdgcn_mfma_f32_16x16x32_bf16(
                    aE[i], bE[j], acc[i][j], 0, 0, 0);
        __builtin_amdgcn_s_setprio(0);
        SB();

        // ---- R3: kf1 mh1 (4 reads) ----
#pragma unroll
        for (int i = 0; i < 4; i++)
            aOm[i] = *(const bf16x8*)&la[(ar0 + 64 + i * 16) * 64 + sw1];
        SB();

        // ---- c1: aEm x bE  (R2+R3 = 12 outstanding) ----
        asm volatile("s_waitcnt lgkmcnt(12)" ::: "memory");   // R1 ready
        SB();
        __builtin_amdgcn_s_setprio(1);
#pragma unroll
        for (int i = 0; i < 4; i++)
#pragma unroll
            for (int j = 0; j < 4; j++)
                acc[4 + i][j] = __builtin_amdgcn_mfma_f32_16x16x32_bf16(
                    aEm[i], bE[j], acc[4 + i][j], 0, 0, 0);
        __builtin_amdgcn_s_setprio(0);
        SB();

        // ---- c2: aO x bO  (R3 = 4 outstanding) ----
        asm volatile("s_waitcnt lgkmcnt(4)" ::: "memory");    // R2 ready
        SB();
        __builtin_amdgcn_s_setprio(1);
#pragma unroll
        for (int i = 0; i < 4; i++)
#pragma unroll
            for (int j = 0; j < 4; j++)
                acc[i][j] = __builtin_amdgcn_mfma_f32_16x16x32_bf16(
                    aO[i], bO[j], acc[i][j], 0, 0, 0);
        __builtin_amdgcn_s_setprio(0);
        SB();

        // ---- c3: aOm x bO ----
        asm volatile("s_waitcnt lgkmcnt(0)" ::: "memory");    // R3 ready
        SB();
        __builtin_amdgcn_s_setprio(1);
#pragma unroll
        for (int i = 0; i < 4; i++)
#pragma unroll
            for (int j = 0; j < 4; j++)
                acc[4 + i][j] = __builtin_amdgcn_mfma_f32_16x16x32_bf16(
                    aOm[i], bO[j], acc[4 + i][j], 0, 0, 0);
        __builtin_amdgcn_s_setprio(0);

        // boundary: next tile's 8 DMA (issued a full tile ago) must land
        if (t + 1 < NT) {
            asm volatile("s_waitcnt vmcnt(0)" ::: "memory");
            __builtin_amdgcn_s_barrier();
        }
        SB();
    }

    // Epilogue. C/D layout (m89-verified): col = lane&15, row = (lane>>4)*4 + q
    const int cr = hi * 4;
    const int cc = fr;
#pragma unroll
    for (int m = 0; m < 8; m++) {
        const int row = m0 + wr * 128 + m * 16 + cr;
#pragma unroll
        for (int n = 0; n < 4; n++) {
            const int col = n0 + wc * 64 + n * 16 + cc;
            const float bv = bz[col];
#pragma unroll
            for (int q = 0; q < 4; q++) {
                float v = acc[m][n][q] + bv;
                if (MODE == 0) v = v > 0.f ? v : 0.f;
                Cz[(size_t)(row + q) * N + col] = (ushort)f2bf(v);
            }
        }
    }
}

// ---------------- small 128x128 GEMM (gate layer) ----------------
template<int MODE>
__global__ __launch_bounds__(256) void gemm_bt(
    const ushort* __restrict__ A,
    const ushort* __restrict__ Bw,
    const float* __restrict__ bias,
    ushort* __restrict__ Cb,
    int M, int N, int K)
{
    __shared__ ushort lA[128 * 64];
    __shared__ ushort lB[128 * 64];

    const int tid  = threadIdx.x;
    const int lane = tid & 63;
    const int wv   = tid >> 6;
    const int wr   = wv >> 1;
    const int wc   = wv & 1;
    const int m0   = blockIdx.x * 128;
    const int n0   = blockIdx.y * 128;

    const int srow = lane >> 3;
    const int scol = (lane & 7) * 8;
    const int fr   = lane & 15;
    const int fk   = (lane >> 4) * 8;

    f32x4 zero4 = {0.f, 0.f, 0.f, 0.f};
    f32x4 acc[4][4];
#pragma unroll
    for (int i = 0; i < 4; i++)
#pragma unroll
        for (int j = 0; j < 4; j++) acc[i][j] = zero4;

    for (int kt = 0; kt < K; kt += 64) {
        __syncthreads();
#pragma unroll
        for (int i = 0; i < 4; i++) {
            const int chunk = wv * 4 + i;
            const int row   = chunk * 8 + srow;
            gload_lds16(A  + (size_t)(m0 + row) * K + kt + scol, &lA[chunk * 512]);
            gload_lds16(Bw + (size_t)(n0 + row) * K + kt + scol, &lB[chunk * 512]);
        }
        __syncthreads();

#pragma unroll
        for (int ks = 0; ks < 2; ks++) {
            bf16x8 aF[4], bF[4];
#pragma unroll
            for (int i = 0; i < 4; i++)
                aF[i] = *(const bf16x8*)&lA[(wr * 64 + i * 16 + fr) * 64 + ks * 32 + fk];
#pragma unroll
            for (int j = 0; j < 4; j++)
                bF[j] = *(const bf16x8*)&lB[(wc * 64 + j * 16 + fr) * 64 + ks * 32 + fk];
#pragma unroll
            for (int i = 0; i < 4; i++)
#pragma unroll
                for (int j = 0; j < 4; j++)
                    acc[i][j] = __builtin_amdgcn_mfma_f32_16x16x32_bf16(
                        aF[i], bF[j], acc[i][j], 0, 0, 0);
        }
    }

    const int cr = (lane >> 4) * 4;
    const int cc = lane & 15;
#pragma unroll
    for (int i = 0; i < 4; i++) {
#pragma unroll
        for (int j = 0; j < 4; j++) {
            const int col = n0 + wc * 64 + j * 16 + cc;
            const float bv = bias[col];
#pragma unroll
            for (int q = 0; q < 4; q++) {
                const int row = m0 + wr * 64 + i * 16 + cr + q;
                float v = acc[i][j][q] + bv;
                if (MODE == 0) v = v > 0.f ? v : 0.f;
                Cb[(size_t)row * N + col] = (ushort)f2bf(v);
            }
        }
    }
}

// ---------------- LayerNorm + relu + residual (in place on z) ----------------
__global__ __launch_bounds__(256) void ln_kernel(
    ushort* __restrict__ z, const ushort* __restrict__ h,
    const float* __restrict__ g, const float* __restrict__ b, int B, int H)
{
    const int r = blockIdx.x;
    const int e = blockIdx.y;
    const int t = threadIdx.x;
    const size_t base = ((size_t)e * B + r) * H + t * 4;
    const float* ge = g + (size_t)e * H;
    const float* be = b + (size_t)e * H;

    bf16x4 zv = *(const bf16x4*)&z[base];
    float zf[4];
#pragma unroll
    for (int j = 0; j < 4; j++) zf[j] = bf2f(zv[j]);

    float s  = zf[0] + zf[1] + zf[2] + zf[3];
    float s2 = zf[0]*zf[0] + zf[1]*zf[1] + zf[2]*zf[2] + zf[3]*zf[3];
#pragma unroll
    for (int off = 32; off; off >>= 1) {
        s  += __shfl_xor(s, off);
        s2 += __shfl_xor(s2, off);
    }
    __shared__ float red[8];
    const int wv = t >> 6, lane = t & 63;
    if (lane == 0) { red[wv] = s; red[4 + wv] = s2; }
    __syncthreads();
    s  = red[0] + red[1] + red[2] + red[3];
    s2 = red[4] + red[5] + red[6] + red[7];

    const float mu  = s / (float)H;
    const float var = s2 / (float)H - mu * mu;
    const float rs  = rsqrtf(var + 1e-5f);

    bf16x4 hv = *(const bf16x4*)&h[base];
    bf16x4 o;
#pragma unroll
    for (int j = 0; j < 4; j++) {
        float gn = (zf[j] - mu) * rs * ge[t * 4 + j] + be[t * 4 + j];
        gn = gn > 0.f ? gn : 0.f;
        o[j] = f2bf(gn + bf2f(hv[j]));
    }
    *(bf16x4*)&z[base] = o;
}

// ---------------- gate: logits = gh @ Wg2^T + bg2 ; softmax over 8 ----------
__global__ __launch_bounds__(256) void gate2_kernel(
    const ushort* __restrict__ gh,   // [B,256] bf16
    const float* __restrict__ Wg2,   // [8,256]
    const float* __restrict__ bg2,   // [8]
    float* __restrict__ gate)        // [B,8]
{
    const int wv = threadIdx.x >> 6, lane = threadIdx.x & 63;
    const int r = blockIdx.x * 4 + wv;

    bf16x4 v = *(const bf16x4*)&gh[(size_t)r * 256 + lane * 4];
    float gf[4];
#pragma unroll
    for (int j = 0; j < 4; j++) gf[j] = bf2f(v[j]);

    float lg[8];
#pragma unroll
    for (int e = 0; e < 8; e++) {
        const float* w = Wg2 + e * 256 + lane * 4;
        float p = gf[0]*w[0] + gf[1]*w[1] + gf[2]*w[2] + gf[3]*w[3];
#pragma unroll
        for (int off = 32; off; off >>= 1) p += __shfl_xor(p, off);
        lg[e] = p + bg2[e];
    }
    float mx = lg[0];
#pragma unroll
    for (int e = 1; e < 8; e++) mx = fmaxf(mx, lg[e]);
    float ex[8], ssum = 0.f;
#pragma unroll
    for (int e = 0; e < 8; e++) { ex[e] = expf(lg[e] - mx); ssum += ex[e]; }
    const float inv = 1.f / ssum;
    float myex = 0.f;
#pragma unroll
    for (int e = 0; e < 8; e++) myex = (lane == e) ? ex[e] : myex;
    if (lane < 8) gate[(size_t)r * 8 + lane] = myex * inv;
}

// ---------------- gated combine: out (+)= sum_el gate[b,e0+el] * eo[el,b,:] --
__global__ __launch_bounds__(256) void combine_kernel(
    const ushort* __restrict__ eo,   // [eg, B, D] bf16
    const float* __restrict__ gate,  // [B, 8]
    float* __restrict__ out,         // [B, D]
    int total4, int e0, int eg, int init)
{
    const size_t BD = (size_t)8192 * 1024;
    int idx = blockIdx.x * 256 + threadIdx.x;
    int stride = gridDim.x * 256;
    for (int t = idx; t < total4; t += stride) {
        int b = t >> 8;                 // D/4 = 256
        int d = (t & 255) << 2;
        float4 s = {0.f, 0.f, 0.f, 0.f};
        for (int el = 0; el < eg; el++) {
            const float g = gate[(size_t)b * 8 + e0 + el];
            bf16x4 v = *(const bf16x4*)&eo[(size_t)el * BD + (size_t)b * 1024 + d];
            s.x += g * bf2f(v.x);
            s.y += g * bf2f(v.y);
            s.z += g * bf2f(v.z);
            s.w += g * bf2f(v.w);
        }
        float4* o = (float4*)&out[(size_t)b * 1024 + d];
        if (init) *o = s;
        else {
            float4 p = *o;
            p.x += s.x; p.y += s.y; p.z += s.z; p.w += s.w;
            *o = p;
        }
    }
}

// ---------------- host ----------------
extern "C" void kernel_launch(void* const* d_in, const int* in_sizes, int n_in,
                              void* d_out, int out_size, void* d_ws, size_t ws_size,
                              hipStream_t stream)
{
    const float* x   = (const float*)d_in[0];
    const float* W0  = (const float*)d_in[1];
    const float* b0  = (const float*)d_in[2];
    const float* W1  = (const float*)d_in[3];
    const float* b1  = (const float*)d_in[4];
    const float* lng = (const float*)d_in[5];
    const float* lnb = (const float*)d_in[6];
    const float* W2  = (const float*)d_in[7];
    const float* b2  = (const float*)d_in[8];
    const float* Wg1 = (const float*)d_in[9];
    const float* bg1 = (const float*)d_in[10];
    const float* Wg2 = (const float*)d_in[11];
    const float* bg2 = (const float*)d_in[12];
    float* out = (float*)d_out;

    const int B = 8192, D = 1024, H = 1024, E = 8, G = 256;

    char* ws = (char*)d_ws;
    ushort* x_bf  = (ushort*)ws;  ws += (size_t)B * D * 2;
    ushort* w0_bf = (ushort*)ws;  ws += (size_t)E * H * D * 2;
    ushort* w1_bf = (ushort*)ws;  ws += (size_t)E * H * H * 2;
    ushort* w2_bf = (ushort*)ws;  ws += (size_t)E * D * H * 2;
    ushort* wg1bf = (ushort*)ws;  ws += (size_t)G * D * 2;
    ushort* gh_bf = (ushort*)ws;  ws += (size_t)B * G * 2;
    float*  gatep = (float*)ws;   ws += (size_t)B * E * 4;

    size_t used  = (size_t)(ws - (char*)d_ws);
    size_t avail = (ws_size > used) ? ws_size - used : 0;
    size_t per_eg = (size_t)B * H * 2 * 2;   // h-buf + z-buf per expert
    int EG = 1;
    for (int cand = 8; cand >= 1; cand >>= 1)
        if ((size_t)cand * per_eg <= avail) { EG = cand; break; }

    ushort* hbuf = (ushort*)ws;
    ushort* zbuf = (ushort*)(ws + (size_t)EG * B * H * 2);

    auto cvt = [&](const float* src, ushort* dst, size_t n) {
        int n4 = (int)(n / 4);
        int blocks = (n4 + 255) / 256;
        if (blocks > 2048) blocks = 2048;
        cvt_kernel<<<dim3(blocks), dim3(256), 0, stream>>>(src, dst, n4);
    };
    cvt(x,   x_bf,  (size_t)B * D);
    cvt(W0,  w0_bf, (size_t)E * H * D);
    cvt(W1,  w1_bf, (size_t)E * H * H);
    cvt(W2,  w2_bf, (size_t)E * D * H);
    cvt(Wg1, wg1bf, (size_t)G * D);

    // gate
    gemm_bt<0><<<dim3(B / 128, G / 128), dim3(256), 0, stream>>>(
        x_bf, wg1bf, bg1, gh_bf, B, G, D);
    gate2_kernel<<<dim3(B / 4), dim3(256), 0, stream>>>(gh_bf, Wg2, bg2, gatep);

    const int cb4 = 2048;
    for (int e0 = 0; e0 < E; e0 += EG) {
        const int eg = (E - e0 < EG) ? (E - e0) : EG;
        // layer0: h = relu(x @ W0[e]^T + b0[e])
        gemm256<0><<<dim3(B / 256, H / 256, eg), dim3(512), 0, stream>>>(
            x_bf, w0_bf + (size_t)e0 * H * D, b0 + (size_t)e0 * H, hbuf,
            B, H, D, 0, (long)H * D, H, (long)B * H);
        // layer1: z = h @ W1[e]^T + b1[e]
        gemm256<1><<<dim3(B / 256, H / 256, eg), dim3(512), 0, stream>>>(
            hbuf, w1_bf + (size_t)e0 * H * H, b1 + (size_t)e0 * H, zbuf,
            B, H, H, (long)B * H, (long)H * H, H, (long)B * H);
        // LN -> relu -> +h
        ln_kernel<<<dim3(B, eg), dim3(256), 0, stream>>>(
            zbuf, hbuf, lng + (size_t)e0 * H, lnb + (size_t)e0 * H, B, H);
        // layer2: eo = hp @ W2[e]^T + b2[e]  (into hbuf)
        gemm256<1><<<dim3(B / 256, D / 256, eg), dim3(512), 0, stream>>>(
            zbuf, w2_bf + (size_t)e0 * D * H, b2 + (size_t)e0 * D, hbuf,
            B, D, H, (long)B * H, (long)D * H, D, (long)B * D);
        // gated combine
        combine_kernel<<<dim3(cb4), dim3(256), 0, stream>>>(
            hbuf, gatep, out, B * (D / 4), e0, eg, (e0 == 0) ? 1 : 0);
    }
}

// Round 13
// 574.177 us; speedup vs baseline: 2.5406x; 1.0126x over previous
//
#include <hip/hip_runtime.h>
#include <stdint.h>

typedef __attribute__((ext_vector_type(8))) short bf16x8;
typedef __attribute__((ext_vector_type(4))) short bf16x4;
typedef __attribute__((ext_vector_type(4))) float f32x4;

#define DEV static __device__ __forceinline__
#define SB() __builtin_amdgcn_sched_barrier(0)

DEV float bf2f(short u) {
    union { float f; uint32_t i; } v;
    v.i = ((uint32_t)(uint16_t)u) << 16;
    return v.f;
}
DEV short f2bf(float f) {
    union { float f; uint32_t i; } v; v.f = f;
    uint32_t r = v.i + 0x7fff + ((v.i >> 16) & 1);
    return (short)(r >> 16);
}

DEV void gload_lds16(const void* g, void* l) {
    __builtin_amdgcn_global_load_lds(
        (__attribute__((address_space(1))) void*)(void*)g,
        (__attribute__((address_space(3))) void*)l,
        16, 0, 0);
}

// ---------------- f32 -> bf16 conversion ----------------
__global__ __launch_bounds__(256) void cvt_kernel(const float* __restrict__ in,
                                                  ushort* __restrict__ out, int n4) {
    int idx = blockIdx.x * 256 + threadIdx.x;
    int stride = gridDim.x * 256;
    for (int i = idx; i < n4; i += stride) {
        float4 v = ((const float4*)in)[i];
        bf16x4 o;
        o.x = f2bf(v.x); o.y = f2bf(v.y); o.z = f2bf(v.z); o.w = f2bf(v.w);
        ((bf16x4*)out)[i] = o;
    }
}

// ==== 256x256 GEMM, BK=64, dbuf, R9 schedule + late-DMA placement ====
// LDS per buf: row-major [256 rows][64 k] bf16 (32 KB), 16B-unit XOR swizzle
// ku ^= (row&7)  (R7/R9-verified: 0 bank conflicts, coalesced 128B staging).
// Per tile t (read buf bi=t&1, stage buf nb); R9's counted gates (4/8/4/0),
// but DMA stages moved AFTER c0/c1 so the early clusters' frag reads are
// serviced before any DMA-LDS-write competes in the shared LDS pipe:
//   R0(8) R1(4) ; lgkm(4)->c0 ; R2(8)+stageA ; lgkm(8)->c1 ;
//   R3(4)+stageB ; lgkm(4)->c2 ; lgkm(0)->c3 ; vmcnt(0) ; BARRIER.
// MODE 0: relu(acc+bias) -> bf16 ;  MODE 1: acc+bias -> bf16
template<int MODE>
__global__ __launch_bounds__(512, 2) void gemm256(
    const ushort* __restrict__ A,
    const ushort* __restrict__ Bw,
    const float* __restrict__ bias,
    ushort* __restrict__ Cb,
    int M, int N, int K,
    long sA, long sB, long sBias, long sC)
{
    __shared__ ushort lA[2][16384];   // 2 x 32 KB
    __shared__ ushort lB[2][16384];

    const int z = blockIdx.z;
    const ushort* Az = A + (size_t)z * sA;
    const ushort* Bz = Bw + (size_t)z * sB;
    const float*  bz = bias + (size_t)z * sBias;
    ushort*       Cz = Cb + (size_t)z * sC;

    const int tid  = threadIdx.x;
    const int lane = tid & 63;
    const int wid  = tid >> 6;        // 0..7
    const int wr   = wid >> 2;        // 0..1  (128 rows)
    const int wc   = wid & 3;         // 0..3  (64 cols)
    const int fr   = lane & 15;
    const int hi   = lane >> 4;       // 0..3
    const int m0   = blockIdx.x * 256;
    const int n0   = blockIdx.y * 256;

    // lane-constant swizzled k-offsets (ushorts) for frag reads
    const int fr8 = fr & 7;
    const int sw0 = ((0 + hi) ^ fr8) * 8;   // kf=0
    const int sw1 = ((4 + hi) ^ fr8) * 8;   // kf=1
    const int ar0 = wr * 128 + fr;
    const int br0 = wc * 64 + fr;

    // staging: pass p, unit g = p*512 + tid; row = g>>3; ku = (g&7)^(row&7)
    long offA[4], offB[4];
    int  dstU[4];
#pragma unroll
    for (int p = 0; p < 4; p++) {
        const int g   = p * 512 + tid;
        const int row = g >> 3;
        const int ku  = (g & 7) ^ (row & 7);
        offA[p] = (long)(m0 + row) * K + ku * 8;
        offB[p] = (long)(n0 + row) * K + ku * 8;
        dstU[p] = (p * 512 + wid * 64) * 8;   // wave-uniform ushort index
    }

    auto stA = [&](int bi, long kt) {
#pragma unroll
        for (int p = 0; p < 4; p++)
            gload_lds16(Az + offA[p] + kt, &lA[bi][dstU[p]]);
    };
    auto stB = [&](int bi, long kt) {
#pragma unroll
        for (int p = 0; p < 4; p++)
            gload_lds16(Bz + offB[p] + kt, &lB[bi][dstU[p]]);
    };

    f32x4 acc[8][4];
#pragma unroll
    for (int i = 0; i < 8; i++)
#pragma unroll
        for (int j = 0; j < 4; j++) acc[i][j] = (f32x4){0.f, 0.f, 0.f, 0.f};

    const int NT = K >> 6;   // BK=64

    // prologue: tile 0 fully staged and drained
    stA(0, 0); stB(0, 0);
    asm volatile("s_waitcnt vmcnt(0)" ::: "memory");
    __builtin_amdgcn_s_barrier();
    SB();

    for (int t = 0; t < NT; t++) {
        const int bi = t & 1, nb = bi ^ 1;
        const long ktn = (long)(t + 1) << 6;
        const ushort* la = lA[bi];
        const ushort* lb = lB[bi];
        bf16x8 aE[4], bE[4], aEm[4], aO[4], bO[4], aOm[4];

        // ---- R0: kf0 mh0 (8 reads) ----
#pragma unroll
        for (int i = 0; i < 4; i++)
            aE[i] = *(const bf16x8*)&la[(ar0 + i * 16) * 64 + sw0];
#pragma unroll
        for (int j = 0; j < 4; j++)
            bE[j] = *(const bf16x8*)&lb[(br0 + j * 16) * 64 + sw0];
        SB();
        // ---- R1: kf0 mh1 (4 reads) ----
#pragma unroll
        for (int i = 0; i < 4; i++)
            aEm[i] = *(const bf16x8*)&la[(ar0 + 64 + i * 16) * 64 + sw0];
        SB();

        // ---- c0: aE x bE  (R1 = 4 outstanding) ----
        asm volatile("s_waitcnt lgkmcnt(4)" ::: "memory");   // R0 ready
        SB();
        __builtin_amdgcn_s_setprio(1);
#pragma unroll
        for (int i = 0; i < 4; i++)
#pragma unroll
            for (int j = 0; j < 4; j++)
                acc[i][j] = __builtin_amdgcn_mfma_f32_16x16x32_bf16(
                    aE[i], bE[j], acc[i][j], 0, 0, 0);
        __builtin_amdgcn_s_setprio(0);
        SB();

        // ---- R2: kf1 mh0 (8 reads), then stage A(t+1) ----
#pragma unroll
        for (int i = 0; i < 4; i++)
            aO[i] = *(const bf16x8*)&la[(ar0 + i * 16) * 64 + sw1];
#pragma unroll
        for (int j = 0; j < 4; j++)
            bO[j] = *(const bf16x8*)&lb[(br0 + j * 16) * 64 + sw1];
        SB();
        if (t + 1 < NT) stA(nb, ktn);
        SB();

        // ---- c1: aEm x bE  (R2 = 8 outstanding) ----
        asm volatile("s_waitcnt lgkmcnt(8)" ::: "memory");   // R1 ready
        SB();
        __builtin_amdgcn_s_setprio(1);
#pragma unroll
        for (int i = 0; i < 4; i++)
#pragma unroll
            for (int j = 0; j < 4; j++)
                acc[4 + i][j] = __builtin_amdgcn_mfma_f32_16x16x32_bf16(
                    aEm[i], bE[j], acc[4 + i][j], 0, 0, 0);
        __builtin_amdgcn_s_setprio(0);
        SB();

        // ---- R3: kf1 mh1 (4 reads), then stage B(t+1) ----
#pragma unroll
        for (int i = 0; i < 4; i++)
            aOm[i] = *(const bf16x8*)&la[(ar0 + 64 + i * 16) * 64 + sw1];
        SB();
        if (t + 1 < NT) stB(nb, ktn);
        SB();

        // ---- c2: aO x bO  (R3 = 4 outstanding) ----
        asm volatile("s_waitcnt lgkmcnt(4)" ::: "memory");   // R2 ready
        SB();
        __builtin_amdgcn_s_setprio(1);
#pragma unroll
        for (int i = 0; i < 4; i++)
#pragma unroll
            for (int j = 0; j < 4; j++)
                acc[i][j] = __builtin_amdgcn_mfma_f32_16x16x32_bf16(
                    aO[i], bO[j], acc[i][j], 0, 0, 0);
        __builtin_amdgcn_s_setprio(0);
        SB();

        // ---- c3: aOm x bO ----
        asm volatile("s_waitcnt lgkmcnt(0)" ::: "memory");   // R3 ready
        SB();
        __builtin_amdgcn_s_setprio(1);
#pragma unroll
        for (int i = 0; i < 4; i++)
#pragma unroll
            for (int j = 0; j < 4; j++)
                acc[4 + i][j] = __builtin_amdgcn_mfma_f32_16x16x32_bf16(
                    aOm[i], bO[j], acc[4 + i][j], 0, 0, 0);
        __builtin_amdgcn_s_setprio(0);

        // boundary: next tile's 8 DMA must land
        if (t + 1 < NT) {
            asm volatile("s_waitcnt vmcnt(0)" ::: "memory");
            __builtin_amdgcn_s_barrier();
        }
        SB();
    }

    // Epilogue. C/D layout (m89-verified): col = lane&15, row = (lane>>4)*4 + q
    const int cr = hi * 4;
    const int cc = fr;
#pragma unroll
    for (int m = 0; m < 8; m++) {
        const int row = m0 + wr * 128 + m * 16 + cr;
#pragma unroll
        for (int n = 0; n < 4; n++) {
            const int col = n0 + wc * 64 + n * 16 + cc;
            const float bv = bz[col];
#pragma unroll
            for (int q = 0; q < 4; q++) {
                float v = acc[m][n][q] + bv;
                if (MODE == 0) v = v > 0.f ? v : 0.f;
                Cz[(size_t)(row + q) * N + col] = (ushort)f2bf(v);
            }
        }
    }
}

// ---------------- small 128x128 GEMM (gate layer) ----------------
template<int MODE>
__global__ __launch_bounds__(256) void gemm_bt(
    const ushort* __restrict__ A,
    const ushort* __restrict__ Bw,
    const float* __restrict__ bias,
    ushort* __restrict__ Cb,
    int M, int N, int K)
{
    __shared__ ushort lA[128 * 64];
    __shared__ ushort lB[128 * 64];

    const int tid  = threadIdx.x;
    const int lane = tid & 63;
    const int wv   = tid >> 6;
    const int wr   = wv >> 1;
    const int wc   = wv & 1;
    const int m0   = blockIdx.x * 128;
    const int n0   = blockIdx.y * 128;

    const int srow = lane >> 3;
    const int scol = (lane & 7) * 8;
    const int fr   = lane & 15;
    const int fk   = (lane >> 4) * 8;

    f32x4 zero4 = {0.f, 0.f, 0.f, 0.f};
    f32x4 acc[4][4];
#pragma unroll
    for (int i = 0; i < 4; i++)
#pragma unroll
        for (int j = 0; j < 4; j++) acc[i][j] = zero4;

    for (int kt = 0; kt < K; kt += 64) {
        __syncthreads();
#pragma unroll
        for (int i = 0; i < 4; i++) {
            const int chunk = wv * 4 + i;
            const int row   = chunk * 8 + srow;
            gload_lds16(A  + (size_t)(m0 + row) * K + kt + scol, &lA[chunk * 512]);
            gload_lds16(Bw + (size_t)(n0 + row) * K + kt + scol, &lB[chunk * 512]);
        }
        __syncthreads();

#pragma unroll
        for (int ks = 0; ks < 2; ks++) {
            bf16x8 aF[4], bF[4];
#pragma unroll
            for (int i = 0; i < 4; i++)
                aF[i] = *(const bf16x8*)&lA[(wr * 64 + i * 16 + fr) * 64 + ks * 32 + fk];
#pragma unroll
            for (int j = 0; j < 4; j++)
                bF[j] = *(const bf16x8*)&lB[(wc * 64 + j * 16 + fr) * 64 + ks * 32 + fk];
#pragma unroll
            for (int i = 0; i < 4; i++)
#pragma unroll
                for (int j = 0; j < 4; j++)
                    acc[i][j] = __builtin_amdgcn_mfma_f32_16x16x32_bf16(
                        aF[i], bF[j], acc[i][j], 0, 0, 0);
        }
    }

    const int cr = (lane >> 4) * 4;
    const int cc = lane & 15;
#pragma unroll
    for (int i = 0; i < 4; i++) {
#pragma unroll
        for (int j = 0; j < 4; j++) {
            const int col = n0 + wc * 64 + j * 16 + cc;
            const float bv = bias[col];
#pragma unroll
            for (int q = 0; q < 4; q++) {
                const int row = m0 + wr * 64 + i * 16 + cr + q;
                float v = acc[i][j][q] + bv;
                if (MODE == 0) v = v > 0.f ? v : 0.f;
                Cb[(size_t)row * N + col] = (ushort)f2bf(v);
            }
        }
    }
}

// ---------------- LayerNorm + relu + residual (in place on z) ----------------
__global__ __launch_bounds__(256) void ln_kernel(
    ushort* __restrict__ z, const ushort* __restrict__ h,
    const float* __restrict__ g, const float* __restrict__ b, int B, int H)
{
    const int r = blockIdx.x;
    const int e = blockIdx.y;
    const int t = threadIdx.x;
    const size_t base = ((size_t)e * B + r) * H + t * 4;
    const float* ge = g + (size_t)e * H;
    const float* be = b + (size_t)e * H;

    bf16x4 zv = *(const bf16x4*)&z[base];
    float zf[4];
#pragma unroll
    for (int j = 0; j < 4; j++) zf[j] = bf2f(zv[j]);

    float s  = zf[0] + zf[1] + zf[2] + zf[3];
    float s2 = zf[0]*zf[0] + zf[1]*zf[1] + zf[2]*zf[2] + zf[3]*zf[3];
#pragma unroll
    for (int off = 32; off; off >>= 1) {
        s  += __shfl_xor(s, off);
        s2 += __shfl_xor(s2, off);
    }
    __shared__ float red[8];
    const int wv = t >> 6, lane = t & 63;
    if (lane == 0) { red[wv] = s; red[4 + wv] = s2; }
    __syncthreads();
    s  = red[0] + red[1] + red[2] + red[3];
    s2 = red[4] + red[5] + red[6] + red[7];

    const float mu  = s / (float)H;
    const float var = s2 / (float)H - mu * mu;
    const float rs  = rsqrtf(var + 1e-5f);

    bf16x4 hv = *(const bf16x4*)&h[base];
    bf16x4 o;
#pragma unroll
    for (int j = 0; j < 4; j++) {
        float gn = (zf[j] - mu) * rs * ge[t * 4 + j] + be[t * 4 + j];
        gn = gn > 0.f ? gn : 0.f;
        o[j] = f2bf(gn + bf2f(hv[j]));
    }
    *(bf16x4*)&z[base] = o;
}

// ---------------- gate: logits = gh @ Wg2^T + bg2 ; softmax over 8 ----------
__global__ __launch_bounds__(256) void gate2_kernel(
    const ushort* __restrict__ gh,   // [B,256] bf16
    const float* __restrict__ Wg2,   // [8,256]
    const float* __restrict__ bg2,   // [8]
    float* __restrict__ gate)        // [B,8]
{
    const int wv = threadIdx.x >> 6, lane = threadIdx.x & 63;
    const int r = blockIdx.x * 4 + wv;

    bf16x4 v = *(const bf16x4*)&gh[(size_t)r * 256 + lane * 4];
    float gf[4];
#pragma unroll
    for (int j = 0; j < 4; j++) gf[j] = bf2f(v[j]);

    float lg[8];
#pragma unroll
    for (int e = 0; e < 8; e++) {
        const float* w = Wg2 + e * 256 + lane * 4;
        float p = gf[0]*w[0] + gf[1]*w[1] + gf[2]*w[2] + gf[3]*w[3];
#pragma unroll
        for (int off = 32; off; off >>= 1) p += __shfl_xor(p, off);
        lg[e] = p + bg2[e];
    }
    float mx = lg[0];
#pragma unroll
    for (int e = 1; e < 8; e++) mx = fmaxf(mx, lg[e]);
    float ex[8], ssum = 0.f;
#pragma unroll
    for (int e = 0; e < 8; e++) { ex[e] = expf(lg[e] - mx); ssum += ex[e]; }
    const float inv = 1.f / ssum;
    float myex = 0.f;
#pragma unroll
    for (int e = 0; e < 8; e++) myex = (lane == e) ? ex[e] : myex;
    if (lane < 8) gate[(size_t)r * 8 + lane] = myex * inv;
}

// ---------------- gated combine: out (+)= sum_el gate[b,e0+el] * eo[el,b,:] --
__global__ __launch_bounds__(256) void combine_kernel(
    const ushort* __restrict__ eo,   // [eg, B, D] bf16
    const float* __restrict__ gate,  // [B, 8]
    float* __restrict__ out,         // [B, D]
    int total4, int e0, int eg, int init)
{
    const size_t BD = (size_t)8192 * 1024;
    int idx = blockIdx.x * 256 + threadIdx.x;
    int stride = gridDim.x * 256;
    for (int t = idx; t < total4; t += stride) {
        int b = t >> 8;                 // D/4 = 256
        int d = (t & 255) << 2;
        float4 s = {0.f, 0.f, 0.f, 0.f};
        for (int el = 0; el < eg; el++) {
            const float g = gate[(size_t)b * 8 + e0 + el];
            bf16x4 v = *(const bf16x4*)&eo[(size_t)el * BD + (size_t)b * 1024 + d];
            s.x += g * bf2f(v.x);
            s.y += g * bf2f(v.y);
            s.z += g * bf2f(v.z);
            s.w += g * bf2f(v.w);
        }
        float4* o = (float4*)&out[(size_t)b * 1024 + d];
        if (init) *o = s;
        else {
            float4 p = *o;
            p.x += s.x; p.y += s.y; p.z += s.z; p.w += s.w;
            *o = p;
        }
    }
}

// ---------------- host ----------------
extern "C" void kernel_launch(void* const* d_in, const int* in_sizes, int n_in,
                              void* d_out, int out_size, void* d_ws, size_t ws_size,
                              hipStream_t stream)
{
    const float* x   = (const float*)d_in[0];
    const float* W0  = (const float*)d_in[1];
    const float* b0  = (const float*)d_in[2];
    const float* W1  = (const float*)d_in[3];
    const float* b1  = (const float*)d_in[4];
    const float* lng = (const float*)d_in[5];
    const float* lnb = (const float*)d_in[6];
    const float* W2  = (const float*)d_in[7];
    const float* b2  = (const float*)d_in[8];
    const float* Wg1 = (const float*)d_in[9];
    const float* bg1 = (const float*)d_in[10];
    const float* Wg2 = (const float*)d_in[11];
    const float* bg2 = (const float*)d_in[12];
    float* out = (float*)d_out;

    const int B = 8192, D = 1024, H = 1024, E = 8, G = 256;

    char* ws = (char*)d_ws;
    ushort* x_bf  = (ushort*)ws;  ws += (size_t)B * D * 2;
    ushort* w0_bf = (ushort*)ws;  ws += (size_t)E * H * D * 2;
    ushort* w1_bf = (ushort*)ws;  ws += (size_t)E * H * H * 2;
    ushort* w2_bf = (ushort*)ws;  ws += (size_t)E * D * H * 2;
    ushort* wg1bf = (ushort*)ws;  ws += (size_t)G * D * 2;
    ushort* gh_bf = (ushort*)ws;  ws += (size_t)B * G * 2;
    float*  gatep = (float*)ws;   ws += (size_t)B * E * 4;

    size_t used  = (size_t)(ws - (char*)d_ws);
    size_t avail = (ws_size > used) ? ws_size - used : 0;
    size_t per_eg = (size_t)B * H * 2 * 2;   // h-buf + z-buf per expert
    int EG = 1;
    for (int cand = 8; cand >= 1; cand >>= 1)
        if ((size_t)cand * per_eg <= avail) { EG = cand; break; }

    ushort* hbuf = (ushort*)ws;
    ushort* zbuf = (ushort*)(ws + (size_t)EG * B * H * 2);

    auto cvt = [&](const float* src, ushort* dst, size_t n) {
        int n4 = (int)(n / 4);
        int blocks = (n4 + 255) / 256;
        if (blocks > 2048) blocks = 2048;
        cvt_kernel<<<dim3(blocks), dim3(256), 0, stream>>>(src, dst, n4);
    };
    cvt(x,   x_bf,  (size_t)B * D);
    cvt(W0,  w0_bf, (size_t)E * H * D);
    cvt(W1,  w1_bf, (size_t)E * H * H);
    cvt(W2,  w2_bf, (size_t)E * D * H);
    cvt(Wg1, wg1bf, (size_t)G * D);

    // gate
    gemm_bt<0><<<dim3(B / 128, G / 128), dim3(256), 0, stream>>>(
        x_bf, wg1bf, bg1, gh_bf, B, G, D);
    gate2_kernel<<<dim3(B / 4), dim3(256), 0, stream>>>(gh_bf, Wg2, bg2, gatep);

    const int cb4 = 2048;
    for (int e0 = 0; e0 < E; e0 += EG) {
        const int eg = (E - e0 < EG) ? (E - e0) : EG;
        // layer0: h = relu(x @ W0[e]^T + b0[e])
        gemm256<0><<<dim3(B / 256, H / 256, eg), dim3(512), 0, stream>>>(
            x_bf, w0_bf + (size_t)e0 * H * D, b0 + (size_t)e0 * H, hbuf,
            B, H, D, 0, (long)H * D, H, (long)B * H);
        // layer1: z = h @ W1[e]^T + b1[e]
        gemm256<1><<<dim3(B / 256, H / 256, eg), dim3(512), 0, stream>>>(
            hbuf, w1_bf + (size_t)e0 * H * H, b1 + (size_t)e0 * H, zbuf,
            B, H, H, (long)B * H, (long)H * H, H, (long)B * H);
        // LN -> relu -> +h
        ln_kernel<<<dim3(B, eg), dim3(256), 0, stream>>>(
            zbuf, hbuf, lng + (size_t)e0 * H, lnb + (size_t)e0 * H, B, H);
        // layer2: eo = hp @ W2[e]^T + b2[e]  (into hbuf)
        gemm256<1><<<dim3(B / 256, D / 256, eg), dim3(512), 0, stream>>>(
            zbuf, w2_bf + (size_t)e0 * D * H, b2 + (size_t)e0 * D, hbuf,
            B, D, H, (long)B * H, (long)D * H, D, (long)B * D);
        // gated combine
        combine_kernel<<<dim3(cb4), dim3(256), 0, stream>>>(
            hbuf, gatep, out, B * (D / 4), e0, eg, (e0 == 0) ? 1 : 0);
    }
}